// Round 1
// baseline (6220.594 us; speedup 1.0000x reference)
//
#include <hip/hip_runtime.h>
#include <hip/hip_bf16.h>

#define N_LABELS 28415
#define EMB 200
#define NKF 200
#define HID 512
#define CTXD 1000
#define BB 4
#define LA 400
#define LT 32
#define TA 398
#define TT 30

// ---------------- transpose: out[N][M] = in[M][N]^T ----------------
__global__ void k_transpose(const float* __restrict__ in, float* __restrict__ out,
                            int M, int N) {
    __shared__ float tile[32][33];
    int x = blockIdx.x * 32 + threadIdx.x;
    int y0 = blockIdx.y * 32;
    #pragma unroll
    for (int j = 0; j < 32; j += 8) {
        int y = y0 + threadIdx.y + j;
        if (x < N && y < M) tile[threadIdx.y + j][threadIdx.x] = in[(size_t)y * N + x];
    }
    __syncthreads();
    int x2 = blockIdx.y * 32 + threadIdx.x;      // output col = input row
    int y2 = blockIdx.x * 32 + threadIdx.y;      // output row = input col
    #pragma unroll
    for (int j = 0; j < 32; j += 8) {
        int yy = y2 + j;
        if (x2 < M && yy < N) out[(size_t)yy * M + x2] = tile[threadIdx.x][threadIdx.y + j];
    }
}

// ---------------- embedding + conv1d(k=3) + relu ----------------
__global__ __launch_bounds__(256) void k_conv(
        const int* __restrict__ tok, const float* __restrict__ emb,
        const float* __restrict__ w, const float* __restrict__ bias,
        float* __restrict__ out, int L, int Tout) {
    int b = blockIdx.x / Tout;
    int t = blockIdx.x % Tout;
    __shared__ float e[3 * EMB];
    for (int idx = threadIdx.x; idx < 3 * EMB; idx += 256) {
        int wofs = idx / EMB, i = idx % EMB;
        e[idx] = emb[(size_t)tok[b * L + t + wofs] * EMB + i];
    }
    __syncthreads();
    int o = threadIdx.x;
    if (o < NKF) {
        float acc = bias[o];
        #pragma unroll 4
        for (int m = 0; m < 3 * EMB; ++m)
            acc = fmaf(e[m], w[(size_t)m * NKF + o], acc);
        out[(size_t)blockIdx.x * NKF + o] = fmaxf(acc, 0.f);
    }
}

// ---------------- edge scatter-add (segment_sum) ----------------
template<int D>
__global__ void k_scatter_add(const int* __restrict__ src, const int* __restrict__ dst,
                              const float* __restrict__ feat, float* __restrict__ out,
                              long long total) {
    long long idx = (long long)blockIdx.x * 256 + threadIdx.x;
    if (idx >= total) return;
    int e = (int)(idx / D), k = (int)(idx % D);
    atomicAdd(&out[(size_t)dst[e] * D + k], feat[(size_t)src[e] * D + k]);
}

// ---------------- f32 GEMM: C[M][ldc] = act(A[M][K] @ Bt[K][N] + bias) ---------
template<int ACT>
__global__ __launch_bounds__(256) void k_gemm(
        const float* __restrict__ A, const float* __restrict__ Bt,
        const float* __restrict__ bias, float* __restrict__ C,
        int M, int N, int K, int ldc) {
    __shared__ float As[8][132];
    __shared__ float Bs[8][132];
    int m0 = blockIdx.x * 128;
    int n0 = blockIdx.y * 128;
    int tx = threadIdx.x & 15, ty = threadIdx.x >> 4;
    float acc[8][8] = {};
    for (int k0 = 0; k0 < K; k0 += 8) {
        for (int idx = threadIdx.x; idx < 1024; idx += 256) {
            int r = idx >> 3, kk = idx & 7;
            int m = m0 + r;
            As[kk][r] = (m < M) ? A[(size_t)m * K + k0 + kk] : 0.f;
        }
        for (int idx = threadIdx.x; idx < 1024; idx += 256) {
            int kk = idx >> 7, c = idx & 127;
            int n = n0 + c;
            Bs[kk][c] = (n < N) ? Bt[(size_t)(k0 + kk) * N + n] : 0.f;
        }
        __syncthreads();
        #pragma unroll
        for (int kk = 0; kk < 8; ++kk) {
            float4 a0 = *(float4*)&As[kk][ty * 8];
            float4 a1 = *(float4*)&As[kk][ty * 8 + 4];
            float4 b0 = *(float4*)&Bs[kk][tx * 8];
            float4 b1 = *(float4*)&Bs[kk][tx * 8 + 4];
            float a[8] = {a0.x, a0.y, a0.z, a0.w, a1.x, a1.y, a1.z, a1.w};
            float bv[8] = {b0.x, b0.y, b0.z, b0.w, b1.x, b1.y, b1.z, b1.w};
            #pragma unroll
            for (int i = 0; i < 8; ++i)
                #pragma unroll
                for (int j = 0; j < 8; ++j)
                    acc[i][j] = fmaf(a[i], bv[j], acc[i][j]);
        }
        __syncthreads();
    }
    #pragma unroll
    for (int i = 0; i < 8; ++i) {
        int m = m0 + ty * 8 + i;
        if (m >= M) break;
        #pragma unroll
        for (int j = 0; j < 8; ++j) {
            int n = n0 + tx * 8 + j;
            if (n < N) {
                float v = acc[i][j] + bias[n];
                if (ACT) v = fmaxf(v, 0.f);
                C[(size_t)m * ldc + n] = v;
            }
        }
    }
}

// ---------------- copy g into label_feature cols 200..399 ----------------
__global__ void k_label_copy(const float* __restrict__ g, float* __restrict__ label) {
    long long idx = (long long)blockIdx.x * 256 + threadIdx.x;
    if (idx >= (long long)N_LABELS * EMB) return;
    int n = (int)(idx / EMB), j = (int)(idx % EMB);
    label[(size_t)n * 400 + 200 + j] = g[idx];
}

// ---------------- fused attention + cf + label dot ----------------
// per block: 8 labels; loops over b. x[b][n] output.
__global__ __launch_bounds__(256) void k_attn(
        const float* __restrict__ convA, const float* __restrict__ convT,
        const float* __restrict__ g, const float* __restrict__ cf_wT,
        const float* __restrict__ cf_b, const float* __restrict__ label,
        float* __restrict__ xout) {
    __shared__ float g_lds[8][EMB];          // 6.4 KB
    __shared__ float conv_lds[28][212];      // 23.7 KB (stride 212: /4 odd -> b128 conflict-free)
    __shared__ float sc[8][TA];              // 12.7 KB (scores -> att weights; reused by title)
    __shared__ float cont[400][12];          // 19.2 KB (content, k-major, q in [0..7])
    __shared__ float xred[8];

    int n0 = blockIdx.x * 8;
    int tid = threadIdx.x;
    int q = tid >> 5, tl = tid & 31;

    for (int idx = tid; idx < 8 * EMB; idx += 256) {
        int qq = idx / EMB, k = idx % EMB;
        int n = n0 + qq;
        g_lds[qq][k] = (n < N_LABELS) ? g[(size_t)n * EMB + k] : 0.f;
    }
    __syncthreads();

    for (int b = 0; b < BB; ++b) {
        for (int half = 0; half < 2; ++half) {
            const float* conv = half ? convT + (size_t)b * TT * EMB
                                     : convA + (size_t)b * TA * EMB;
            const int T = half ? TT : TA;
            const int kofs = half ? 200 : 0;

            // ---- scores ----
            for (int t0 = 0; t0 < T; t0 += 28) {
                int tcnt = min(28, T - t0);
                __syncthreads();
                for (int idx = tid; idx < tcnt * EMB; idx += 256) {
                    int tt = idx / EMB, k = idx % EMB;
                    conv_lds[tt][k] = conv[(size_t)(t0 + tt) * EMB + k];
                }
                __syncthreads();
                if (tl < tcnt) {
                    const float4* gp = (const float4*)&g_lds[q][0];
                    const float4* cp = (const float4*)&conv_lds[tl][0];
                    float s = 0.f;
                    #pragma unroll 5
                    for (int kk = 0; kk < EMB / 4; ++kk) {
                        float4 gv = gp[kk], cv = cp[kk];
                        s += gv.x * cv.x + gv.y * cv.y + gv.z * cv.z + gv.w * cv.w;
                    }
                    sc[q][t0 + tl] = s;
                }
            }
            __syncthreads();

            // ---- softmax over T (32 threads per q, wave-local) ----
            float m = -1e30f;
            for (int t = tl; t < T; t += 32) m = fmaxf(m, sc[q][t]);
            #pragma unroll
            for (int off = 16; off; off >>= 1) m = fmaxf(m, __shfl_xor(m, off));
            float ssum = 0.f;
            for (int t = tl; t < T; t += 32) {
                float ev = __expf(sc[q][t] - m);
                sc[q][t] = ev;
                ssum += ev;
            }
            #pragma unroll
            for (int off = 16; off; off >>= 1) ssum += __shfl_xor(ssum, off);
            float inv = 1.f / ssum;
            for (int t = tl; t < T; t += 32) sc[q][t] *= inv;

            // ---- content: cont[kofs+k][q] = sum_t att[t]*conv[t][k] ----
            float kacc[7] = {};
            for (int t0 = 0; t0 < T; t0 += 28) {
                int tcnt = min(28, T - t0);
                __syncthreads();
                for (int idx = tid; idx < tcnt * EMB; idx += 256) {
                    int tt = idx / EMB, k = idx % EMB;
                    conv_lds[tt][k] = conv[(size_t)(t0 + tt) * EMB + k];
                }
                __syncthreads();
                for (int t = 0; t < tcnt; ++t) {
                    float a = sc[q][t0 + t];
                    #pragma unroll
                    for (int j = 0; j < 7; ++j) {
                        int k = tl + 32 * j;
                        if (k < EMB) kacc[j] = fmaf(a, conv_lds[t][k], kacc[j]);
                    }
                }
            }
            #pragma unroll
            for (int j = 0; j < 7; ++j) {
                int k = tl + 32 * j;
                if (k < EMB) cont[kofs + k][q] = kacc[j];
            }
        }
        __syncthreads();
        if (tid < 8) xred[tid] = 0.f;
        __syncthreads();

        // ---- cf: xf[q][d] = tanh(sum_k cont[k][q]*cf_w[d][k] + cf_b[d]); x += xf*label ----
        if (tid < 200) {
            int qh = tid / 100, dq = tid % 100;
            int d0 = dq * 4;
            float4 bv = *(const float4*)&cf_b[d0];
            float acc[4][4];
            #pragma unroll
            for (int i = 0; i < 4; ++i) {
                acc[i][0] = bv.x; acc[i][1] = bv.y; acc[i][2] = bv.z; acc[i][3] = bv.w;
            }
            for (int k = 0; k < 400; ++k) {
                float4 cq = *(float4*)&cont[k][qh * 4];
                float4 w = *(const float4*)&cf_wT[(size_t)k * 400 + d0];
                float cqa[4] = {cq.x, cq.y, cq.z, cq.w};
                float wa[4] = {w.x, w.y, w.z, w.w};
                #pragma unroll
                for (int i = 0; i < 4; ++i)
                    #pragma unroll
                    for (int j = 0; j < 4; ++j)
                        acc[i][j] = fmaf(cqa[i], wa[j], acc[i][j]);
            }
            #pragma unroll
            for (int i = 0; i < 4; ++i) {
                int n = n0 + qh * 4 + i;
                if (n < N_LABELS) {
                    float4 lf = *(const float4*)&label[(size_t)n * 400 + d0];
                    float part = tanhf(acc[i][0]) * lf.x + tanhf(acc[i][1]) * lf.y
                               + tanhf(acc[i][2]) * lf.z + tanhf(acc[i][3]) * lf.w;
                    atomicAdd(&xred[qh * 4 + i], part);
                }
            }
        }
        __syncthreads();
        if (tid < 8 && n0 + tid < N_LABELS)
            xout[(size_t)b * N_LABELS + n0 + tid] = xred[tid];
        __syncthreads();
    }
}

// ---------------- CorNet ----------------
__global__ void k_sigmoid(const float* __restrict__ in, float* __restrict__ out, int n) {
    int i = blockIdx.x * 256 + threadIdx.x;
    if (i < n) out[i] = 1.f / (1.f + __expf(-in[i]));
}

__global__ __launch_bounds__(256) void k_cor_ctx(
        const float* __restrict__ s, const float* __restrict__ w_dc,
        const float* __restrict__ b_dc, float* __restrict__ ctx) {
    int c = blockIdx.x;
    const float* wr = w_dc + (size_t)c * N_LABELS;
    float acc[BB] = {};
    for (int n = threadIdx.x; n < N_LABELS; n += 256) {
        float w = wr[n];
        #pragma unroll
        for (int b = 0; b < BB; ++b)
            acc[b] = fmaf(w, s[(size_t)b * N_LABELS + n], acc[b]);
    }
    __shared__ float red[4][BB];
    #pragma unroll
    for (int b = 0; b < BB; ++b) {
        float v = acc[b];
        #pragma unroll
        for (int off = 32; off; off >>= 1) v += __shfl_xor(v, off);
        if ((threadIdx.x & 63) == 0) red[threadIdx.x >> 6][b] = v;
    }
    __syncthreads();
    if (threadIdx.x < BB) {
        int b = threadIdx.x;
        float v = red[0][b] + red[1][b] + red[2][b] + red[3][b] + b_dc[c];
        ctx[b * CTXD + c] = v > 0.f ? v : expm1f(v);
    }
}

__global__ __launch_bounds__(256) void k_cor_upd(
        const float* __restrict__ ctx, const float* __restrict__ w_cd,
        const float* __restrict__ b_cd, float* __restrict__ x) {
    __shared__ float cl[BB][256];
    int c0 = blockIdx.y * 256;
    int cnt = min(256, CTXD - c0);
    for (int idx = threadIdx.x; idx < BB * 256; idx += 256) {
        int b = idx >> 8, cc = idx & 255;
        cl[b][cc] = (c0 + cc < CTXD) ? ctx[b * CTXD + c0 + cc] : 0.f;
    }
    __syncthreads();
    int n = blockIdx.x * 256 + threadIdx.x;
    if (n >= N_LABELS) return;
    const float* wr = w_cd + (size_t)n * CTXD + c0;
    float acc[BB] = {};
    for (int cc = 0; cc < cnt; cc += 4) {
        float4 w4 = *(const float4*)&wr[cc];
        #pragma unroll
        for (int b = 0; b < BB; ++b) {
            float4 c4 = *(const float4*)&cl[b][cc];
            acc[b] += w4.x * c4.x + w4.y * c4.y + w4.z * c4.z + w4.w * c4.w;
        }
    }
    #pragma unroll
    for (int b = 0; b < BB; ++b) {
        float add = acc[b] + (blockIdx.y == 0 ? b_cd[n] : 0.f);
        atomicAdd(&x[(size_t)b * N_LABELS + n], add);
    }
}

// ---------------- host launch ----------------
extern "C" void kernel_launch(void* const* d_in, const int* in_sizes, int n_in,
                              void* d_out, int out_size, void* d_ws, size_t ws_size,
                              hipStream_t stream) {
    const int*   input_seq   = (const int*)d_in[0];
    const int*   input_title = (const int*)d_in[1];
    const float* g_node      = (const float*)d_in[2];
    const int*   edge_src    = (const int*)d_in[3];
    const int*   edge_dst    = (const int*)d_in[4];
    const float* emb_table   = (const float*)d_in[5];
    const float* conv_w      = (const float*)d_in[6];
    const float* conv_b      = (const float*)d_in[7];
    const float* cf_w        = (const float*)d_in[8];
    const float* cf_b        = (const float*)d_in[9];
    const float* gcn1_w      = (const float*)d_in[10];
    const float* gcn1_b      = (const float*)d_in[11];
    const float* gcn2_w      = (const float*)d_in[12];
    const float* gcn2_b      = (const float*)d_in[13];
    const float* w_dc1 = (const float*)d_in[14];
    const float* b_dc1 = (const float*)d_in[15];
    const float* w_cd1 = (const float*)d_in[16];
    const float* b_cd1 = (const float*)d_in[17];
    const float* w_dc2 = (const float*)d_in[18];
    const float* b_dc2 = (const float*)d_in[19];
    const float* w_cd2 = (const float*)d_in[20];
    const float* b_cd2 = (const float*)d_in[21];
    const int E = in_sizes[3];

    float* ws = (float*)d_ws;
    size_t off = 0;
    float* cf_wT = ws + off; off += 160000;
    float* g1T   = ws + off; off += 102400;
    float* g2T   = ws + off; off += 102400;
    float* convA = ws + off; off += (size_t)BB * TA * NKF;
    float* convT = ws + off; off += (size_t)BB * TT * NKF;
    float* agg1  = ws + off; off += (size_t)N_LABELS * EMB;
    float* h1    = ws + off; off += (size_t)N_LABELS * HID;
    float* agg2  = ws + off; off += (size_t)N_LABELS * HID;
    float* label = ws + off; off += (size_t)N_LABELS * 400;
    float* x     = ws + off; off += (size_t)BB * N_LABELS;
    float* s     = ws + off; off += (size_t)BB * N_LABELS;
    float* ctx   = ws + off; off += (size_t)BB * CTXD;

    dim3 tb(32, 8);
    hipLaunchKernelGGL(k_transpose, dim3(13, 13), tb, 0, stream, cf_w, cf_wT, 400, 400);
    hipLaunchKernelGGL(k_transpose, dim3(7, 16), tb, 0, stream, gcn1_w, g1T, HID, EMB);
    hipLaunchKernelGGL(k_transpose, dim3(16, 7), tb, 0, stream, gcn2_w, g2T, EMB, HID);

    hipLaunchKernelGGL(k_conv, dim3(BB * TA), dim3(256), 0, stream,
                       input_seq, emb_table, conv_w, conv_b, convA, LA, TA);
    hipLaunchKernelGGL(k_conv, dim3(BB * TT), dim3(256), 0, stream,
                       input_title, emb_table, conv_w, conv_b, convT, LT, TT);

    hipMemsetAsync(agg1, 0, (size_t)N_LABELS * EMB * 4, stream);
    {
        long long total = (long long)E * EMB;
        int blocks = (int)((total + 255) / 256);
        hipLaunchKernelGGL((k_scatter_add<EMB>), dim3(blocks), dim3(256), 0, stream,
                           edge_src, edge_dst, g_node, agg1, total);
    }
    hipLaunchKernelGGL((k_gemm<1>), dim3(222, 4), dim3(256), 0, stream,
                       agg1, g1T, gcn1_b, h1, N_LABELS, HID, EMB, HID);
    hipMemsetAsync(agg2, 0, (size_t)N_LABELS * HID * 4, stream);
    {
        long long total = (long long)E * HID;
        int blocks = (int)((total + 255) / 256);
        hipLaunchKernelGGL((k_scatter_add<HID>), dim3(blocks), dim3(256), 0, stream,
                           edge_src, edge_dst, h1, agg2, total);
    }
    hipLaunchKernelGGL((k_gemm<0>), dim3(222, 2), dim3(256), 0, stream,
                       agg2, g2T, gcn2_b, label, N_LABELS, EMB, HID, 400);
    {
        long long total = (long long)N_LABELS * EMB;
        int blocks = (int)((total + 255) / 256);
        hipLaunchKernelGGL(k_label_copy, dim3(blocks), dim3(256), 0, stream, g_node, label);
    }

    hipLaunchKernelGGL(k_attn, dim3((N_LABELS + 7) / 8), dim3(256), 0, stream,
                       convA, convT, g_node, cf_wT, cf_b, label, x);

    const float* wdc[2] = {w_dc1, w_dc2};
    const float* bdc[2] = {b_dc1, b_dc2};
    const float* wcd[2] = {w_cd1, w_cd2};
    const float* bcd[2] = {b_cd1, b_cd2};
    int nx = BB * N_LABELS;
    for (int i = 0; i < 2; ++i) {
        hipLaunchKernelGGL(k_sigmoid, dim3((nx + 255) / 256), dim3(256), 0, stream, x, s, nx);
        hipLaunchKernelGGL(k_cor_ctx, dim3(CTXD), dim3(256), 0, stream, s, wdc[i], bdc[i], ctx);
        hipLaunchKernelGGL(k_cor_upd, dim3((N_LABELS + 255) / 256, 4), dim3(256), 0, stream,
                           ctx, wcd[i], bcd[i], x);
    }
    hipLaunchKernelGGL(k_sigmoid, dim3((nx + 255) / 256), dim3(256), 0, stream, x, (float*)d_out, nx);
}